// Round 1
// 434.240 us; speedup vs baseline: 1.0357x; 1.0357x over previous
//
#include <hip/hip_runtime.h>

// SelfAttentionLayer: B=8, N=2048, D=1024, fp32 in/out.
// R8: 256x256 tile, BK=64, 8 waves (2m x 4n, 128x64 per wave), 4-phase
// interleaved schedule per K-tile (T3+T4): each phase = {ds_read subtile |
// issue 2 global_load_lds | barrier | lgkmcnt(0) | setprio(1) 16xMFMA
// setprio(0) | barrier}, counted vmcnt(6) once per K-tile (never 0 in
// steady state). LDS 128 KiB double-buffered, rows XOR-swizzled
// (chunk ^= row&7 over 8x16B chunks) via pre-swizzled global source.
// Race-freedom: every glds issued in phase p targets regions last read in
// phase <= p-1 (A q0/q2 dead after ph0 -> staged ph1; B halves dead after
// ph1 -> staged ph2/ph3; A q1/q3 dead after ph2 -> staged next tile ph0
// into the other buffer).

typedef _Float16 f16;
typedef _Float16 f16x4 __attribute__((ext_vector_type(4)));
typedef _Float16 f16x8 __attribute__((ext_vector_type(8)));
typedef float f32x4 __attribute__((ext_vector_type(4)));

#define Nn_ 2048
#define Dd 1024

typedef const __attribute__((address_space(1))) void gvoid;
typedef __attribute__((address_space(3))) void lvoid;

__device__ __forceinline__ void glds16(const void* g, void* l) {
    __builtin_amdgcn_global_load_lds((gvoid*)g, (lvoid*)l, 16, 0, 0);
}
#define BARRIER()  asm volatile("s_barrier" ::: "memory")
#define LGKM0()    asm volatile("s_waitcnt lgkmcnt(0)" ::: "memory")
#define VM6()      asm volatile("s_waitcnt vmcnt(6)" ::: "memory")
#define VM0()      asm volatile("s_waitcnt vmcnt(0)" ::: "memory")
#define PRIO1()    __builtin_amdgcn_s_setprio(1)
#define PRIO0()    __builtin_amdgcn_s_setprio(0)
#define MFMA(a, b, c) __builtin_amdgcn_mfma_f32_16x16x32_f16((a), (b), (c), 0, 0, 0)

// ---------------- fp32 -> fp16 convert ----------------
__global__ void cvt_kernel(const float4* __restrict__ in, f16x4* __restrict__ out, int n4) {
    int i = blockIdx.x * 256 + threadIdx.x;
    if (i >= n4) return;
    float4 f = in[i];
    f16x4 h;
    h.x = (_Float16)f.x; h.y = (_Float16)f.y; h.z = (_Float16)f.z; h.w = (_Float16)f.w;
    out[i] = h;
}

// ---------------- bias concat: bqkv[3072] = [bq|bk|bv] ----------------
__global__ void concat_bias(const float* __restrict__ bq, const float* __restrict__ bk,
                            const float* __restrict__ bv, float* __restrict__ o) {
    int i = blockIdx.x * 256 + threadIdx.x;
    if (i >= 3072) return;
    o[i] = (i < 1024) ? bq[i] : (i < 2048 ? bk[i - 1024] : bv[i - 2048]);
}

// ---------------- BT GEMM, 256m x 256n tile, 512 threads --------------------
// C[m][n] = sum_k A[m][k] * Bm[n][k].
// LDS per buffer: A 256x64 f16 (32KB) + B 256x64 f16 (32KB); 2 buffers = 128KB.
// Row = 128B = 8 chunks of 16B; logical chunk c stored at physical c^(row&7)
// (loader pre-swizzles the GLOBAL source column; LDS dest stays linear).
// mode 2: fp32 out row-major, no bias       (S-GEMM, PV->d_out)
// mode 3: merged QKV (N=3072, 12 n-tiles): by<4 -> qh, by<8 -> kh,
//         else vT[b][e][tok] via LDS transpose (coalesced stores).
__global__ __launch_bounds__(512) void gemm_bt(
    const f16* __restrict__ A, const f16* __restrict__ Bm,
    const float* __restrict__ bias, void* __restrict__ Cout,
    f16* __restrict__ qh, f16* __restrict__ kh, f16* __restrict__ vT,
    int K, int lda, int ldb, int ldc, int mode,
    long aStride, long bStride, long cStride)
{
    __shared__ f16 sm[65536];   // 128 KiB: two 64 KiB stages
    const int tid = threadIdx.x;
    const int lane = tid & 63, wid = tid >> 6;
    const int quad = lane >> 4, l16 = lane & 15;
    const int wm = wid & 1;          // 2 m-positions (128 rows each)
    const int wn = wid >> 1;         // 4 n-positions (64 cols each)
    const long m0 = (long)blockIdx.x * 256, n0 = (long)blockIdx.y * 256;
    A += (long)blockIdx.z * aStride;
    Bm += (long)blockIdx.z * bStride;

    // ---- staging pointers: thread t covers row lr of each 64-row quarter,
    // source chunk pre-swizzled so linear LDS dest yields chunk^(row&7) layout.
    const int lr = tid >> 3;
    const int sc8 = ((tid & 7) ^ (lr & 7)) * 8;
    const f16* pa = A + (m0 + lr) * (long)lda + sc8;
    const f16* pb = Bm + (n0 + lr) * (long)ldb + sc8;
    const long a64 = 64L * lda, b64 = 64L * ldb;

    // ---- fragment read bases (f16 units). row&7 == l16&7 for all frags.
    const int aRow = (wm * 128 + l16) * 64;
    const int bRow = (wn * 64 + l16) * 64;
    const int co0 = (quad ^ (l16 & 7)) * 8;          // k-half 0
    const int co1 = ((quad + 4) ^ (l16 & 7)) * 8;    // k-half 1

    f32x4 acc[8][4];
#pragma unroll
    for (int i = 0; i < 8; i++)
#pragma unroll
        for (int j = 0; j < 4; j++) acc[i][j] = 0.0f;

    const int nk = K >> 6;

    // ---- prologue: tile0 complete (A q0-3, B q0-3), tile1 minus A q1/q3.
#pragma unroll
    for (int q = 0; q < 4; ++q) glds16(pa + q * a64, sm + tid * 8 + q * 4096);
#pragma unroll
    for (int q = 0; q < 4; ++q) glds16(pb + q * b64, sm + 16384 + tid * 8 + q * 4096);
    if (nk > 1) {
        glds16(pa + 0 * a64 + 64, sm + 32768 + tid * 8);
        glds16(pa + 2 * a64 + 64, sm + 32768 + tid * 8 + 2 * 4096);
#pragma unroll
        for (int q = 0; q < 4; ++q)
            glds16(pb + q * b64 + 64, sm + 32768 + 16384 + tid * 8 + q * 4096);
        VM6(); BARRIER();
    } else {
        VM0(); BARRIER();
    }

    f16x8 af[2][4], bf0[2][2], bf1[2][2];
    for (int t = 0; t < nk; ++t) {
        const int bo = (t & 1) << 15;       // current buffer (f16 offset)
        const int bn = bo ^ 32768;          // other buffer (tile t+1)
        const f16* As = sm + bo;
        const f16* Bs = As + 16384;
        const long kt1 = (long)(t + 1) * 64, kt2 = (long)(t + 2) * 64;

        // ---------- phase 0: mh=0, nh=0 ----------
#pragma unroll
        for (int i = 0; i < 4; ++i) {
            af[0][i] = *(const f16x8*)(As + aRow + i * 1024 + co0);
            af[1][i] = *(const f16x8*)(As + aRow + i * 1024 + co1);
        }
#pragma unroll
        for (int j = 0; j < 2; ++j) {
            bf0[0][j] = *(const f16x8*)(Bs + bRow + j * 1024 + co0);
            bf0[1][j] = *(const f16x8*)(Bs + bRow + j * 1024 + co1);
        }
        if (t + 1 < nk) {   // tile t+1 A q1,q3 -> other buffer (read last at t-1 ph2)
            glds16(pa + 1 * a64 + kt1, sm + bn + tid * 8 + 1 * 4096);
            glds16(pa + 3 * a64 + kt1, sm + bn + tid * 8 + 3 * 4096);
        }
        BARRIER(); LGKM0(); PRIO1();
#pragma unroll
        for (int i = 0; i < 4; ++i)
#pragma unroll
            for (int j = 0; j < 2; ++j) {
                acc[i][j] = MFMA(af[0][i], bf0[0][j], acc[i][j]);
                acc[i][j] = MFMA(af[1][i], bf0[1][j], acc[i][j]);
            }
        PRIO0(); BARRIER();

        // ---------- phase 1: mh=0, nh=1 ----------
#pragma unroll
        for (int j = 0; j < 2; ++j) {
            bf1[0][j] = *(const f16x8*)(Bs + bRow + 2048 + j * 1024 + co0);
            bf1[1][j] = *(const f16x8*)(Bs + bRow + 2048 + j * 1024 + co1);
        }
        if (t + 2 < nk) {   // tile t+2 A q0,q2 -> current buffer (dead after ph0)
            glds16(pa + 0 * a64 + kt2, sm + bo + tid * 8);
            glds16(pa + 2 * a64 + kt2, sm + bo + tid * 8 + 2 * 4096);
        }
        BARRIER(); LGKM0(); PRIO1();
#pragma unroll
        for (int i = 0; i < 4; ++i)
#pragma unroll
            for (int j = 0; j < 2; ++j) {
                acc[i][2 + j] = MFMA(af[0][i], bf1[0][j], acc[i][2 + j]);
                acc[i][2 + j] = MFMA(af[1][i], bf1[1][j], acc[i][2 + j]);
            }
        PRIO0(); BARRIER();

        // ---------- phase 2: mh=1, nh=0 ----------
#pragma unroll
        for (int i = 0; i < 4; ++i) {
            af[0][i] = *(const f16x8*)(As + aRow + 4096 + i * 1024 + co0);
            af[1][i] = *(const f16x8*)(As + aRow + 4096 + i * 1024 + co1);
        }
        if (t + 2 < nk) {   // tile t+2 B q0,q1 (B rows 0-127 dead after ph1)
            glds16(pb + 0 * b64 + kt2, sm + bo + 16384 + tid * 8);
            glds16(pb + 1 * b64 + kt2, sm + bo + 16384 + tid * 8 + 4096);
        }
        BARRIER(); LGKM0(); PRIO1();
#pragma unroll
        for (int i = 0; i < 4; ++i)
#pragma unroll
            for (int j = 0; j < 2; ++j) {
                acc[4 + i][j] = MFMA(af[0][i], bf0[0][j], acc[4 + i][j]);
                acc[4 + i][j] = MFMA(af[1][i], bf0[1][j], acc[4 + i][j]);
            }
        PRIO0(); BARRIER();

        // ---------- phase 3: mh=1, nh=1 ----------
        if (t + 2 < nk) {   // tile t+2 B q2,q3 (B rows 128-255 dead after ph1)
            glds16(pb + 2 * b64 + kt2, sm + bo + 16384 + tid * 8 + 2 * 4096);
            glds16(pb + 3 * b64 + kt2, sm + bo + 16384 + tid * 8 + 3 * 4096);
        }
        BARRIER(); PRIO1();
#pragma unroll
        for (int i = 0; i < 4; ++i)
#pragma unroll
            for (int j = 0; j < 2; ++j) {
                acc[4 + i][2 + j] = MFMA(af[0][i], bf1[0][j], acc[4 + i][2 + j]);
                acc[4 + i][2 + j] = MFMA(af[1][i], bf1[1][j], acc[4 + i][2 + j]);
            }
        PRIO0();
        // once-per-K-tile counted wait: drains ALL of tile t+1 (8 loads),
        // leaves tile t+2's 6 in flight. Edge tiles drain fully.
        if (t + 2 < nk) { VM6(); } else { VM0(); }
        BARRIER();
    }

    if (mode == 2) {
        float* O = (float*)Cout + (long)blockIdx.z * cStride;
#pragma unroll
        for (int ct = 0; ct < 4; ct++) {
            long n = n0 + wn * 64 + ct * 16 + l16;
#pragma unroll
            for (int rt = 0; rt < 8; rt++) {
                long mb = m0 + wm * 128 + rt * 16 + quad * 4;
#pragma unroll
                for (int r = 0; r < 4; r++)
                    O[(mb + r) * ldc + n] = acc[rt][ct][r];
            }
        }
    } else {  // mode 3: merged QKV routing (n-tile = 256 wide)
        if (blockIdx.y < 8) {
            f16* O = (blockIdx.y < 4) ? qh : kh;
#pragma unroll
            for (int ct = 0; ct < 4; ct++) {
                long n = n0 + wn * 64 + ct * 16 + l16;
                float bs = bias[n];
                long n1 = n & 1023;
#pragma unroll
                for (int rt = 0; rt < 8; rt++) {
                    long mb = m0 + wm * 128 + rt * 16 + quad * 4;
#pragma unroll
                    for (int r = 0; r < 4; r++)
                        O[(mb + r) * 1024 + n1] = (f16)(acc[rt][ct][r] + bs);
                }
            }
        } else {
            // V: transpose 256m x 256n tile through LDS in four 64-col groups;
            // write vT[b][e][tok] with contiguous rows.
            const long nb = n0 - 2048;
            const long vbase = (m0 >> 11) * (long)(Dd * Nn_) + (m0 & 2047);
#pragma unroll
            for (int g = 0; g < 4; ++g) {
                __syncthreads();
                if (wn == g) {   // 2 waves (wm=0,1) own this 64-col group
#pragma unroll
                    for (int ct = 0; ct < 4; ++ct) {
                        int cl = ct * 16 + l16;                 // 0..63
                        float bs = bias[n0 + g * 64 + cl];
#pragma unroll
                        for (int rt = 0; rt < 8; rt++) {
                            int row = wm * 128 + rt * 16 + quad * 4;  // + r, 0..255
#pragma unroll
                            for (int r = 0; r < 4; r++)
                                sm[cl * 264 + row + r] = (f16)(acc[rt][ct][r] + bs);
                        }
                    }
                }
                __syncthreads();
                const int rowi = tid >> 3, c = (tid & 7) * 32;
                f16* dst = vT + vbase + (nb + g * 64 + rowi) * (long)Nn_ + c;
                const f16* src = sm + rowi * 264 + c;
                *(f16x8*)(dst) = *(const f16x8*)(src);
                *(f16x8*)(dst + 8) = *(const f16x8*)(src + 8);
                *(f16x8*)(dst + 16) = *(const f16x8*)(src + 16);
                *(f16x8*)(dst + 24) = *(const f16x8*)(src + 24);
            }
        }
    }
}

// ---------------- row softmax, P fp16 written in-place over S fp32 --------
__global__ __launch_bounds__(256) void softmax_rows(float* __restrict__ S) {
    const int row = blockIdx.x * 4 + (threadIdx.x >> 6);
    const int lane = threadIdx.x & 63;
    float* Sr = S + (long)row * 2048;
    const float4* R4 = (const float4*)Sr;
    float4 t[8];
#pragma unroll
    for (int i = 0; i < 8; i++) t[i] = R4[lane + 64 * i];
    float mx = -1e30f;
#pragma unroll
    for (int i = 0; i < 8; i++)
        mx = fmaxf(mx, fmaxf(fmaxf(t[i].x, t[i].y), fmaxf(t[i].z, t[i].w)));
#pragma unroll
    for (int off = 1; off < 64; off <<= 1) mx = fmaxf(mx, __shfl_xor(mx, off, 64));
    float se = 0.0f;
#pragma unroll
    for (int i = 0; i < 8; i++) {
        t[i].x = __expf(t[i].x - mx); t[i].y = __expf(t[i].y - mx);
        t[i].z = __expf(t[i].z - mx); t[i].w = __expf(t[i].w - mx);
        se += t[i].x + t[i].y + t[i].z + t[i].w;
    }
#pragma unroll
    for (int off = 1; off < 64; off <<= 1) se += __shfl_xor(se, off, 64);
    const float li = 1.0f / se;
    f16x4* P4 = (f16x4*)Sr;
#pragma unroll
    for (int i = 0; i < 8; i++) {
        f16x4 h;
        h.x = (_Float16)(t[i].x * li); h.y = (_Float16)(t[i].y * li);
        h.z = (_Float16)(t[i].z * li); h.w = (_Float16)(t[i].w * li);
        P4[lane + 64 * i] = h;
    }
}

extern "C" void kernel_launch(void* const* d_in, const int* in_sizes, int n_in,
                              void* d_out, int out_size, void* d_ws, size_t ws_size,
                              hipStream_t stream) {
    const float* x  = (const float*)d_in[0];
    const float* Wq = (const float*)d_in[1];
    const float* bq = (const float*)d_in[2];
    const float* Wk = (const float*)d_in[3];
    const float* bk = (const float*)d_in[4];
    const float* Wv = (const float*)d_in[5];
    const float* bv = (const float*)d_in[6];

    f16* wsh = (f16*)d_ws;
    dim3 blk(512);
    const bool full = ws_size >= 234881024ULL;  // 224 MiB full-batch path

    if (full) {
        f16* qh  = wsh;
        f16* kh  = wsh + 16777216;
        f16* vT  = wsh + 33554432;
        float* S = (float*)(wsh + 50331648);        // 33554432 floats
        f16* xh  = wsh + 50331648;                  // overlaid in S (dead later)
        f16* Wh  = wsh + 67108864;
        float* bqkv = (float*)(wsh + 70254592);

        cvt_kernel<<<16384, 256, 0, stream>>>((const float4*)x, (f16x4*)xh, 4194304);
        cvt_kernel<<<1024, 256, 0, stream>>>((const float4*)Wq, (f16x4*)Wh, 262144);
        cvt_kernel<<<1024, 256, 0, stream>>>((const float4*)Wk, (f16x4*)(Wh + 1048576), 262144);
        cvt_kernel<<<1024, 256, 0, stream>>>((const float4*)Wv, (f16x4*)(Wh + 2097152), 262144);
        concat_bias<<<12, 256, 0, stream>>>(bq, bk, bv, bqkv);

        // QKV: M=16384 (64 m-tiles), N=3072 (12 n-tiles)
        gemm_bt<<<dim3(64, 12, 1), blk, 0, stream>>>(
            xh, Wh, bqkv, nullptr, qh, kh, vT,
            1024, 1024, 1024, 0, 3, 0, 0, 0);
        // S = Q K^T : per batch 8 m-tiles x 8 n-tiles
        gemm_bt<<<dim3(8, 8, 8), blk, 0, stream>>>(
            qh, kh, nullptr, S, nullptr, nullptr, nullptr,
            1024, 1024, 1024, 2048, 2,
            (long)Nn_ * Dd, (long)Nn_ * Dd, (long)Nn_ * Nn_);
        softmax_rows<<<4096, 256, 0, stream>>>(S);
        // out = P V : per batch 8 m-tiles x 4 n-tiles
        gemm_bt<<<dim3(8, 4, 8), blk, 0, stream>>>(
            (const f16*)S, vT, nullptr, d_out, nullptr, nullptr, nullptr,
            2048, 4096, 2048, 1024, 2,
            (long)Nn_ * 4096, (long)Dd * Nn_, (long)Nn_ * Dd);
    } else {
        f16* xh  = wsh;
        f16* Wh  = wsh + 16777216;
        float* bqkv = (float*)(wsh + 19922944);
        f16* qh  = wsh + 19929088;
        f16* kh  = qh + 16777216;
        f16* vT  = kh + 16777216;
        float* S = (float*)(vT + 16777216);

        cvt_kernel<<<16384, 256, 0, stream>>>((const float4*)x, (f16x4*)xh, 4194304);
        cvt_kernel<<<1024, 256, 0, stream>>>((const float4*)Wq, (f16x4*)Wh, 262144);
        cvt_kernel<<<1024, 256, 0, stream>>>((const float4*)Wk, (f16x4*)(Wh + 1048576), 262144);
        cvt_kernel<<<1024, 256, 0, stream>>>((const float4*)Wv, (f16x4*)(Wh + 2097152), 262144);
        concat_bias<<<12, 256, 0, stream>>>(bq, bk, bv, bqkv);

        gemm_bt<<<dim3(64, 12, 1), blk, 0, stream>>>(
            xh, Wh, bqkv, nullptr, qh, kh, vT,
            1024, 1024, 1024, 0, 3, 0, 0, 0);

        for (int h = 0; h < 2; ++h) {
            const long b0 = 4L * h;
            gemm_bt<<<dim3(8, 8, 4), blk, 0, stream>>>(
                qh + b0 * Nn_ * Dd, kh + b0 * Nn_ * Dd, nullptr, S,
                nullptr, nullptr, nullptr,
                1024, 1024, 1024, 2048, 2,
                (long)Nn_ * Dd, (long)Nn_ * Dd, (long)Nn_ * Nn_);
            softmax_rows<<<2048, 256, 0, stream>>>(S);
            gemm_bt<<<dim3(8, 4, 4), blk, 0, stream>>>(
                (const f16*)S, vT + b0 * Dd * Nn_, nullptr,
                (float*)d_out + b0 * Nn_ * Dd, nullptr, nullptr, nullptr,
                2048, 4096, 2048, 1024, 2,
                (long)Nn_ * 4096, (long)Dd * Nn_, (long)Nn_ * Dd);
        }
    }
}